// Round 1
// baseline (633.651 us; speedup 1.0000x reference)
//
#include <hip/hip_runtime.h>
#include <math.h>

#define FIN 128
#define NH 8
#define HC 128
#define HD (NH*HC)   // 1024
#define NC 18
#define NEG 0.2f

__device__ __forceinline__ float lrelu(float v){ return v > 0.f ? v : NEG*v; }

// ---------------- CSR build (by destination) ----------------
__global__ void hist_k(const int* __restrict__ ei, int E0, int N, int* __restrict__ deg){
  int e = blockIdx.x*256 + threadIdx.x;
  int tot = E0 + N;
  if (e >= tot) return;
  int dst = (e < E0) ? ei[E0 + e] : (e - E0);
  atomicAdd(&deg[dst], 1);
}

__global__ __launch_bounds__(1024) void scan_k(const int* __restrict__ deg, int N,
                                               int* __restrict__ off, int* __restrict__ cursor){
  __shared__ int wsum[16];
  __shared__ int s_carry;
  int t = threadIdx.x, lane = t & 63, wid = t >> 6;
  if (t == 0) s_carry = 0;
  __syncthreads();
  for (int base = 0; base < N; base += 1024) {
    int i = base + t;
    int v = (i < N) ? deg[i] : 0;
    int x = v;
    #pragma unroll
    for (int o = 1; o < 64; o <<= 1) {
      int y = __shfl_up(x, o, 64);
      if (lane >= o) x += y;
    }
    if (lane == 63) wsum[wid] = x;
    __syncthreads();
    if (wid == 0) {
      int wv = (lane < 16) ? wsum[lane] : 0;
      #pragma unroll
      for (int o = 1; o < 16; o <<= 1) {
        int y = __shfl_up(wv, o, 64);
        if (lane >= o) wv += y;
      }
      if (lane < 16) wsum[lane] = wv;
    }
    __syncthreads();
    int woff = (wid > 0) ? wsum[wid-1] : 0;
    int carry = s_carry;
    int exc = x - v + woff + carry;
    if (i < N) { off[i] = exc; cursor[i] = exc; }
    __syncthreads();
    if (t == 1023) s_carry = carry + wsum[15];
    __syncthreads();
  }
  if (t == 0) off[N] = s_carry;
}

__global__ void scatter_k(const int* __restrict__ ei, int E0, int N,
                          int* __restrict__ cursor, int* __restrict__ csr){
  int e = blockIdx.x*256 + threadIdx.x;
  int tot = E0 + N;
  if (e >= tot) return;
  int src, dst;
  if (e < E0) { src = ei[e]; dst = ei[E0 + e]; }
  else        { src = e - E0; dst = src; }
  int p = atomicAdd(&cursor[dst], 1);
  csr[p] = src;
}

// ---------------- GEMM1: g1 = x @ W1  (fp32, K=128) ----------------
__global__ __launch_bounds__(256) void gemm1_k(const float* __restrict__ x,
                                               const float* __restrict__ W,
                                               float* __restrict__ g1, int N){
  __shared__ float sX[64][FIN+1];   // [m][k] pad->129
  __shared__ float sB[FIN][64+4];   // [k][n] pad->68
  int t = threadIdx.x;
  int bm = blockIdx.x * 64;
  int bn = blockIdx.y * 64;
  #pragma unroll
  for (int i = 0; i < 32; ++i) {
    int idx = i*256 + t;
    int m = idx >> 7, k = idx & 127;
    int gm = bm + m;
    sX[m][k] = (gm < N) ? x[(size_t)gm*FIN + k] : 0.f;
  }
  #pragma unroll
  for (int i = 0; i < 32; ++i) {
    int idx = i*256 + t;
    int k = idx >> 6, n = idx & 63;
    sB[k][n] = W[(size_t)k*HD + bn + n];
  }
  __syncthreads();
  int tm = (t >> 4) << 2;
  int tn = (t & 15) << 2;
  float4 acc[4];
  #pragma unroll
  for (int i = 0; i < 4; ++i) acc[i] = make_float4(0.f,0.f,0.f,0.f);
  #pragma unroll 8
  for (int k = 0; k < FIN; ++k) {
    float a0 = sX[tm+0][k], a1 = sX[tm+1][k], a2 = sX[tm+2][k], a3 = sX[tm+3][k];
    float4 b = *(const float4*)&sB[k][tn];
    acc[0].x += a0*b.x; acc[0].y += a0*b.y; acc[0].z += a0*b.z; acc[0].w += a0*b.w;
    acc[1].x += a1*b.x; acc[1].y += a1*b.y; acc[1].z += a1*b.z; acc[1].w += a1*b.w;
    acc[2].x += a2*b.x; acc[2].y += a2*b.y; acc[2].z += a2*b.z; acc[2].w += a2*b.w;
    acc[3].x += a3*b.x; acc[3].y += a3*b.y; acc[3].z += a3*b.z; acc[3].w += a3*b.w;
  }
  #pragma unroll
  for (int i = 0; i < 4; ++i) {
    int row = bm + tm + i;
    if (row < N) *(float4*)&g1[(size_t)row*HD + bn + tn] = acc[i];
  }
}

// ---------------- alpha1: per-node attention logits ----------------
__global__ __launch_bounds__(256) void alpha1_k(const float* __restrict__ g1,
    const float* __restrict__ a1s, const float* __restrict__ a1d,
    float* __restrict__ as1, float* __restrict__ ad1, int N){
  int n = blockIdx.x, t = threadIdx.x;
  int h = t >> 5;
  int cc = (t & 31) << 2;
  float4 hv = *(const float4*)&g1[(size_t)n*HD + (t << 2)];
  float4 av = *(const float4*)&a1s[h*HC + cc];
  float4 bv = *(const float4*)&a1d[h*HC + cc];
  float s = hv.x*av.x + hv.y*av.y + hv.z*av.z + hv.w*av.w;
  float d = hv.x*bv.x + hv.y*bv.y + hv.z*bv.z + hv.w*bv.w;
  #pragma unroll
  for (int o = 16; o > 0; o >>= 1) {
    s += __shfl_xor(s, o, 32);
    d += __shfl_xor(d, o, 32);
  }
  if ((t & 31) == 0) { as1[n*NH + h] = s; ad1[n*NH + h] = d; }
}

// ---------------- attn1: per-dst softmax + weighted gather (8 heads x 128 ch) ----------------
__global__ __launch_bounds__(256) void attn1_k(const float* __restrict__ g1,
    const float* __restrict__ as1, const float* __restrict__ ad1,
    const int* __restrict__ off, const int* __restrict__ csr,
    const float* __restrict__ b1, float* __restrict__ hrelu, int N){
  int d = blockIdx.x, t = threadIdx.x;
  __shared__ float adl[NH], m_s[NH], zinv_s[NH];
  __shared__ int   srcs[32];
  __shared__ float w_s[32][NH];
  int beg = off[d], end = off[d+1], deg = end - beg;
  if (t < NH) adl[t] = ad1[d*NH + t];
  __syncthreads();
  int h = t >> 5, ln = t & 31;
  // pass 1: per-head max over in-edges
  float lm = -1e30f;
  for (int j = ln; j < deg; j += 32) {
    int s = csr[beg + j];
    lm = fmaxf(lm, lrelu(as1[s*NH + h] + adl[h]));
  }
  #pragma unroll
  for (int o = 16; o > 0; o >>= 1) lm = fmaxf(lm, __shfl_xor(lm, o, 32));
  if (ln == 0) m_s[h] = lm;
  __syncthreads();
  float mh = m_s[h];
  // pass 2: denominator
  float lz = 0.f;
  for (int j = ln; j < deg; j += 32) {
    int s = csr[beg + j];
    lz += __expf(lrelu(as1[s*NH + h] + adl[h]) - mh);
  }
  #pragma unroll
  for (int o = 16; o > 0; o >>= 1) lz += __shfl_xor(lz, o, 32);
  if (ln == 0) zinv_s[h] = 1.f / (lz + 1e-16f);
  __syncthreads();
  // pass 3: chunked weighted accumulation, 4 channels/thread
  int c4 = t << 2;
  int ch = t >> 5;   // head of this thread's 4 channels
  float4 acc = make_float4(0.f,0.f,0.f,0.f);
  for (int c0 = 0; c0 < deg; c0 += 32) {
    int cn = min(32, deg - c0);
    __syncthreads();
    if (t < cn) srcs[t] = csr[beg + c0 + t];
    __syncthreads();
    int j8 = t >> 3, h8 = t & 7;
    if (j8 < cn) {
      int s = srcs[j8];
      float e = lrelu(as1[s*NH + h8] + adl[h8]);
      w_s[j8][h8] = __expf(e - m_s[h8]) * zinv_s[h8];
    }
    __syncthreads();
    for (int j = 0; j < cn; ++j) {
      int s = srcs[j];
      float wv = w_s[j][ch];
      float4 v = *(const float4*)&g1[(size_t)s*HD + c4];
      acc.x += wv*v.x; acc.y += wv*v.y; acc.z += wv*v.z; acc.w += wv*v.w;
    }
  }
  float4 bv = *(const float4*)&b1[c4];
  float4 o;
  o.x = fmaxf(acc.x + bv.x, 0.f);
  o.y = fmaxf(acc.y + bv.y, 0.f);
  o.z = fmaxf(acc.z + bv.z, 0.f);
  o.w = fmaxf(acc.w + bv.w, 0.f);
  *(float4*)&hrelu[(size_t)d*HD + c4] = o;
}

// ---------------- GEMM2 (+alpha2 fused): g2 = hrelu @ W2, K=1024, NC=18 ----------------
__global__ __launch_bounds__(256) void gemm2_k(const float* __restrict__ hrelu,
    const float* __restrict__ W2, const float* __restrict__ a2s_g, const float* __restrict__ a2d_g,
    float* __restrict__ g2, float* __restrict__ as2, float* __restrict__ ad2, int N){
  __shared__ float sH[4][64][33];
  __shared__ float red[4][64][19];
  int t = threadIdx.x, lane = t & 63, wid = t >> 6;
  int n0 = blockIdx.x * 64;
  float acc[NC];
  #pragma unroll
  for (int c = 0; c < NC; ++c) acc[c] = 0.f;
  int kbase = wid * 256;
  for (int c0 = 0; c0 < 256; c0 += 32) {
    #pragma unroll
    for (int it = 0; it < 32; ++it) {
      int idx = it*64 + lane;
      int nn = idx >> 5, kk = idx & 31;
      int gn = n0 + nn;
      sH[wid][nn][kk] = (gn < N) ? hrelu[(size_t)gn*HD + kbase + c0 + kk] : 0.f;
    }
    // wave-private region: lockstep wave, no block barrier needed
    #pragma unroll
    for (int kk = 0; kk < 32; ++kk) {
      float a = sH[wid][lane][kk];
      const float* wr = &W2[(size_t)(kbase + c0 + kk)*NC];   // wave-uniform -> s_load
      #pragma unroll
      for (int c = 0; c < NC; ++c) acc[c] += a * wr[c];
    }
  }
  #pragma unroll
  for (int c = 0; c < NC; ++c) red[wid][lane][c] = acc[c];
  __syncthreads();
  if (wid == 0) {
    int n = n0 + lane;
    if (n < N) {
      float tot[NC];
      #pragma unroll
      for (int c = 0; c < NC; ++c)
        tot[c] = red[0][lane][c] + red[1][lane][c] + red[2][lane][c] + red[3][lane][c];
      float s = 0.f, dd = 0.f;
      #pragma unroll
      for (int c = 0; c < NC; ++c) {
        s  += tot[c]*a2s_g[c];
        dd += tot[c]*a2d_g[c];
        g2[(size_t)n*NC + c] = tot[c];
      }
      as2[n] = s; ad2[n] = dd;
    }
  }
}

// ---------------- attn2: wave-per-dst softmax + 18-ch gather ----------------
__global__ __launch_bounds__(256) void attn2_k(const float* __restrict__ g2,
    const float* __restrict__ as2, const float* __restrict__ ad2,
    const int* __restrict__ off, const int* __restrict__ csr,
    const float* __restrict__ b2, float* __restrict__ out, int N){
  int t = threadIdx.x, lane = t & 63, wid = t >> 6;
  int d = blockIdx.x*4 + wid;
  if (d >= N) return;
  int beg = off[d], end = off[d+1];
  float adv = ad2[d];
  float lm = -1e30f;
  for (int j = beg + lane; j < end; j += 64)
    lm = fmaxf(lm, lrelu(as2[csr[j]] + adv));
  #pragma unroll
  for (int o = 32; o > 0; o >>= 1) lm = fmaxf(lm, __shfl_xor(lm, o, 64));
  float lz = 0.f;
  for (int j = beg + lane; j < end; j += 64)
    lz += __expf(lrelu(as2[csr[j]] + adv) - lm);
  #pragma unroll
  for (int o = 32; o > 0; o >>= 1) lz += __shfl_xor(lz, o, 64);
  float zinv = 1.f / (lz + 1e-16f);
  if (lane < NC) {
    float acc = 0.f;
    for (int j = beg; j < end; ++j) {
      int s = csr[j];
      float w = __expf(lrelu(as2[s] + adv) - lm) * zinv;
      acc += w * g2[(size_t)s*NC + lane];
    }
    out[(size_t)d*NC + lane] = acc + b2[lane];
  }
}

extern "C" void kernel_launch(void* const* d_in, const int* in_sizes, int n_in,
                              void* d_out, int out_size, void* d_ws, size_t ws_size,
                              hipStream_t stream){
  const float* x   = (const float*)d_in[0];
  const int*   ei  = (const int*)d_in[1];
  const float* W1  = (const float*)d_in[2];
  const float* a1s = (const float*)d_in[3];
  const float* a1d = (const float*)d_in[4];
  const float* b1  = (const float*)d_in[5];
  const float* W2  = (const float*)d_in[6];
  const float* a2s = (const float*)d_in[7];
  const float* a2d = (const float*)d_in[8];
  const float* b2  = (const float*)d_in[9];
  float* out = (float*)d_out;
  int N  = in_sizes[0] / FIN;
  int E0 = in_sizes[1] / 2;
  int Etot = E0 + N;

  float* g1    = (float*)d_ws;
  float* hrelu = g1 + (size_t)N*HD;
  float* as1   = hrelu + (size_t)N*HD;
  float* ad1   = as1 + (size_t)N*NH;
  float* g2    = ad1 + (size_t)N*NH;
  float* as2   = g2 + (size_t)N*NC;
  float* ad2   = as2 + N;
  int* deg     = (int*)(ad2 + N);
  int* off     = deg + N;
  int* cursor  = off + N + 1;
  int* csr     = cursor + N;

  hipMemsetAsync(deg, 0, sizeof(int)*(size_t)N, stream);
  hist_k<<<(Etot+255)/256, 256, 0, stream>>>(ei, E0, N, deg);
  scan_k<<<1, 1024, 0, stream>>>(deg, N, off, cursor);
  scatter_k<<<(Etot+255)/256, 256, 0, stream>>>(ei, E0, N, cursor, csr);

  dim3 g1grid((N+63)/64, HD/64);
  gemm1_k<<<g1grid, 256, 0, stream>>>(x, W1, g1, N);
  alpha1_k<<<N, 256, 0, stream>>>(g1, a1s, a1d, as1, ad1, N);
  attn1_k<<<N, 256, 0, stream>>>(g1, as1, ad1, off, csr, b1, hrelu, N);
  gemm2_k<<<(N+63)/64, 256, 0, stream>>>(hrelu, W2, a2s, a2d, g2, as2, ad2, N);
  attn2_k<<<(N+3)/4, 256, 0, stream>>>(g2, as2, ad2, off, csr, b2, out, N);
}

// Round 2
// 413.624 us; speedup vs baseline: 1.5319x; 1.5319x over previous
//
#include <hip/hip_runtime.h>
#include <math.h>

#define FIN 128
#define NH 8
#define HC 128
#define HD (NH*HC)   // 1024
#define NC 18
#define NEG 0.2f

__device__ __forceinline__ float lrelu(float v){ return v > 0.f ? v : NEG*v; }

// round-to-nearest-even fp32 -> bf16
__device__ __forceinline__ unsigned short f2b(float f){
  unsigned u = __float_as_uint(f);
  unsigned r = (u + 0x7fffu + ((u >> 16) & 1u)) >> 16;
  return (unsigned short)r;
}
__device__ __forceinline__ float b2f(unsigned short u){
  return __uint_as_float(((unsigned)u) << 16);
}
__device__ __forceinline__ float b2f_lo(unsigned u){ return __uint_as_float(u << 16); }
__device__ __forceinline__ float b2f_hi(unsigned u){ return __uint_as_float(u & 0xffff0000u); }

// ---------------- CSR build (by destination) ----------------
__global__ void hist_k(const int* __restrict__ ei, int E0, int N, int* __restrict__ deg){
  int e = blockIdx.x*256 + threadIdx.x;
  int tot = E0 + N;
  if (e >= tot) return;
  int dst = (e < E0) ? ei[E0 + e] : (e - E0);
  atomicAdd(&deg[dst], 1);
}

__global__ __launch_bounds__(1024) void scan_k(const int* __restrict__ deg, int N,
                                               int* __restrict__ off, int* __restrict__ cursor){
  __shared__ int wsum[16];
  __shared__ int s_carry;
  int t = threadIdx.x, lane = t & 63, wid = t >> 6;
  if (t == 0) s_carry = 0;
  __syncthreads();
  for (int base = 0; base < N; base += 1024) {
    int i = base + t;
    int v = (i < N) ? deg[i] : 0;
    int x = v;
    #pragma unroll
    for (int o = 1; o < 64; o <<= 1) {
      int y = __shfl_up(x, o, 64);
      if (lane >= o) x += y;
    }
    if (lane == 63) wsum[wid] = x;
    __syncthreads();
    if (wid == 0) {
      int wv = (lane < 16) ? wsum[lane] : 0;
      #pragma unroll
      for (int o = 1; o < 16; o <<= 1) {
        int y = __shfl_up(wv, o, 64);
        if (lane >= o) wv += y;
      }
      if (lane < 16) wsum[lane] = wv;
    }
    __syncthreads();
    int woff = (wid > 0) ? wsum[wid-1] : 0;
    int carry = s_carry;
    int exc = x - v + woff + carry;
    if (i < N) { off[i] = exc; cursor[i] = exc; }
    __syncthreads();
    if (t == 1023) s_carry = carry + wsum[15];
    __syncthreads();
  }
  if (t == 0) off[N] = s_carry;
}

__global__ void scatter_k(const int* __restrict__ ei, int E0, int N,
                          int* __restrict__ cursor, int* __restrict__ csr){
  int e = blockIdx.x*256 + threadIdx.x;
  int tot = E0 + N;
  if (e >= tot) return;
  int src, dst;
  if (e < E0) { src = ei[e]; dst = ei[E0 + e]; }
  else        { src = e - E0; dst = src; }
  int p = atomicAdd(&cursor[dst], 1);
  csr[p] = src;
}

// ---------------- GEMM1: g1b = bf16(x @ W1)  (fp32 compute, K=128) ----------------
__global__ __launch_bounds__(256) void gemm1_k(const float* __restrict__ x,
                                               const float* __restrict__ W,
                                               unsigned short* __restrict__ g1b, int N){
  __shared__ float sX[64][FIN+1];
  __shared__ float sB[FIN][64+4];
  int t = threadIdx.x;
  int bm = blockIdx.x * 64;
  int bn = blockIdx.y * 64;
  #pragma unroll
  for (int i = 0; i < 32; ++i) {
    int idx = i*256 + t;
    int m = idx >> 7, k = idx & 127;
    int gm = bm + m;
    sX[m][k] = (gm < N) ? x[(size_t)gm*FIN + k] : 0.f;
  }
  #pragma unroll
  for (int i = 0; i < 32; ++i) {
    int idx = i*256 + t;
    int k = idx >> 6, n = idx & 63;
    sB[k][n] = W[(size_t)k*HD + bn + n];
  }
  __syncthreads();
  int tm = (t >> 4) << 2;
  int tn = (t & 15) << 2;
  float4 acc[4];
  #pragma unroll
  for (int i = 0; i < 4; ++i) acc[i] = make_float4(0.f,0.f,0.f,0.f);
  #pragma unroll 8
  for (int k = 0; k < FIN; ++k) {
    float a0 = sX[tm+0][k], a1 = sX[tm+1][k], a2 = sX[tm+2][k], a3 = sX[tm+3][k];
    float4 b = *(const float4*)&sB[k][tn];
    acc[0].x += a0*b.x; acc[0].y += a0*b.y; acc[0].z += a0*b.z; acc[0].w += a0*b.w;
    acc[1].x += a1*b.x; acc[1].y += a1*b.y; acc[1].z += a1*b.z; acc[1].w += a1*b.w;
    acc[2].x += a2*b.x; acc[2].y += a2*b.y; acc[2].z += a2*b.z; acc[2].w += a2*b.w;
    acc[3].x += a3*b.x; acc[3].y += a3*b.y; acc[3].z += a3*b.z; acc[3].w += a3*b.w;
  }
  #pragma unroll
  for (int i = 0; i < 4; ++i) {
    int row = bm + tm + i;
    if (row < N) {
      float4 a = acc[i];
      ushort4 o;
      o.x = f2b(a.x); o.y = f2b(a.y); o.z = f2b(a.z); o.w = f2b(a.w);
      *(ushort4*)&g1b[(size_t)row*HD + bn + tn] = o;
    }
  }
}

// ---------------- alpha1: per-node attention logits from bf16 h ----------------
__global__ __launch_bounds__(256) void alpha1_k(const unsigned short* __restrict__ g1b,
    const float* __restrict__ a1s, const float* __restrict__ a1d,
    float* __restrict__ as1, float* __restrict__ ad1, int N){
  int n = blockIdx.x, t = threadIdx.x;
  int h = t >> 5;
  int cc = (t & 31) << 2;
  uint2 raw = *(const uint2*)(g1b + (size_t)n*HD + (t << 2));
  float h0 = b2f_lo(raw.x), h1 = b2f_hi(raw.x), h2 = b2f_lo(raw.y), h3 = b2f_hi(raw.y);
  float4 av = *(const float4*)&a1s[h*HC + cc];
  float4 bv = *(const float4*)&a1d[h*HC + cc];
  float s = h0*av.x + h1*av.y + h2*av.z + h3*av.w;
  float d = h0*bv.x + h1*bv.y + h2*bv.z + h3*bv.w;
  #pragma unroll
  for (int o = 16; o > 0; o >>= 1) {
    s += __shfl_xor(s, o, 32);
    d += __shfl_xor(d, o, 32);
  }
  if ((t & 31) == 0) { as1[n*NH + h] = s; ad1[n*NH + h] = d; }
}

// ---------------- attn1: wave-per-dst online softmax + bf16 weighted gather ----------------
__global__ __launch_bounds__(256) void attn1_k(const unsigned short* __restrict__ g1b,
    const float* __restrict__ as1, const float* __restrict__ ad1,
    const int* __restrict__ off, const int* __restrict__ csr,
    const float* __restrict__ b1, unsigned short* __restrict__ hb, int N){
  int t = threadIdx.x, lane = t & 63, wid = t >> 6;
  int d = blockIdx.x*4 + wid;
  if (d >= N) return;
  int beg = off[d], end = off[d+1], deg = end - beg;

  // phase 1: online per-head max/sum.  lane -> (j = lane>>3 strided 8, h = lane&7)
  int hr = lane & 7;
  float adr = ad1[d*NH + hr];
  float m = -1e30f, z = 0.f;
  for (int j = lane >> 3; j < deg; j += 8) {
    int s = csr[beg + j];
    float e = lrelu(as1[s*NH + hr] + adr);
    if (e > m) { z = z*__expf(m - e) + 1.f; m = e; }
    else       { z += __expf(e - m); }
  }
  #pragma unroll
  for (int o = 8; o < 64; o <<= 1) {
    float mo = __shfl_xor(m, o, 64), zo = __shfl_xor(z, o, 64);
    float mn = fmaxf(m, mo);
    z = z*__expf(m - mn) + zo*__expf(mo - mn);
    m = mn;
  }
  // redistribute to gather layout: this lane covers channels [lane*16, lane*16+16) -> head lane>>3
  int hg = lane >> 3;
  float mg   = __shfl(m,   hg, 64);
  float zg   = __shfl(z,   hg, 64);
  float adg  = __shfl(adr, hg, 64);
  float zinv = 1.f / (zg + 1e-16f);

  // phase 2: weighted gather, 16 bf16 channels per lane
  float acc[16];
  #pragma unroll
  for (int i = 0; i < 16; ++i) acc[i] = 0.f;
  for (int j = 0; j < deg; ++j) {
    int s = csr[beg + j];
    float e = lrelu(as1[s*NH + hg] + adg);
    float w = __expf(e - mg) * zinv;
    const uint4* p = (const uint4*)(g1b + (size_t)s*HD) + lane*2;
    uint4 r0 = p[0], r1 = p[1];
    acc[ 0] += w*b2f_lo(r0.x); acc[ 1] += w*b2f_hi(r0.x);
    acc[ 2] += w*b2f_lo(r0.y); acc[ 3] += w*b2f_hi(r0.y);
    acc[ 4] += w*b2f_lo(r0.z); acc[ 5] += w*b2f_hi(r0.z);
    acc[ 6] += w*b2f_lo(r0.w); acc[ 7] += w*b2f_hi(r0.w);
    acc[ 8] += w*b2f_lo(r1.x); acc[ 9] += w*b2f_hi(r1.x);
    acc[10] += w*b2f_lo(r1.y); acc[11] += w*b2f_hi(r1.y);
    acc[12] += w*b2f_lo(r1.z); acc[13] += w*b2f_hi(r1.z);
    acc[14] += w*b2f_lo(r1.w); acc[15] += w*b2f_hi(r1.w);
  }
  // epilogue: + b1, relu, pack bf16
  int cb = lane*16;
  uint o[8];
  #pragma unroll
  for (int q = 0; q < 4; ++q) {
    float4 bv = *(const float4*)&b1[cb + q*4];
    float v0 = fmaxf(acc[q*4+0] + bv.x, 0.f);
    float v1 = fmaxf(acc[q*4+1] + bv.y, 0.f);
    float v2 = fmaxf(acc[q*4+2] + bv.z, 0.f);
    float v3 = fmaxf(acc[q*4+3] + bv.w, 0.f);
    o[q*2+0] = (unsigned)f2b(v0) | ((unsigned)f2b(v1) << 16);
    o[q*2+1] = (unsigned)f2b(v2) | ((unsigned)f2b(v3) << 16);
  }
  uint4* dst = (uint4*)(hb + (size_t)d*HD) + lane*2;
  dst[0] = make_uint4(o[0], o[1], o[2], o[3]);
  dst[1] = make_uint4(o[4], o[5], o[6], o[7]);
}

// ---------------- GEMM2 (+alpha2 fused): g2 = hrelu @ W2, W2 staged bf16 in LDS ----------------
__global__ __launch_bounds__(256) void gemm2_k(const unsigned short* __restrict__ hb,
    const float* __restrict__ W2, const float* __restrict__ a2s_g, const float* __restrict__ a2d_g,
    float* __restrict__ g2, float* __restrict__ as2, float* __restrict__ ad2, int N){
  __shared__ unsigned short sW[HD*NC];       // 36.9 KB
  __shared__ float red[4][64][NC+1];         // 19.5 KB
  int t = threadIdx.x, lane = t & 63, wid = t >> 6;
  int n0 = blockIdx.x * 64;
  // stage W2 as bf16
  #pragma unroll
  for (int i = 0; i < (HD*NC)/256; ++i) {
    int idx = i*256 + t;
    sW[idx] = f2b(W2[idx]);
  }
  __syncthreads();
  int n = n0 + lane;
  bool valid = (n < N);
  float acc[NC];
  #pragma unroll
  for (int c = 0; c < NC; ++c) acc[c] = 0.f;
  int k0beg = wid * 256;
  for (int k0 = k0beg; k0 < k0beg + 256; k0 += 8) {
    uint4 raw = valid ? *(const uint4*)(hb + (size_t)n*HD + k0) : make_uint4(0,0,0,0);
    float a[8];
    a[0]=b2f_lo(raw.x); a[1]=b2f_hi(raw.x); a[2]=b2f_lo(raw.y); a[3]=b2f_hi(raw.y);
    a[4]=b2f_lo(raw.z); a[5]=b2f_hi(raw.z); a[6]=b2f_lo(raw.w); a[7]=b2f_hi(raw.w);
    #pragma unroll
    for (int kk = 0; kk < 8; ++kk) {
      const unsigned* wr = (const unsigned*)(sW + (size_t)(k0 + kk)*NC);
      float av = a[kk];
      #pragma unroll
      for (int c2 = 0; c2 < NC/2; ++c2) {
        unsigned u = wr[c2];
        acc[2*c2+0] += av * b2f_lo(u);
        acc[2*c2+1] += av * b2f_hi(u);
      }
    }
  }
  #pragma unroll
  for (int c = 0; c < NC; ++c) red[wid][lane][c] = acc[c];
  __syncthreads();
  if (wid == 0 && valid) {
    float tot[NC];
    #pragma unroll
    for (int c = 0; c < NC; ++c)
      tot[c] = red[0][lane][c] + red[1][lane][c] + red[2][lane][c] + red[3][lane][c];
    float s = 0.f, dd = 0.f;
    #pragma unroll
    for (int c = 0; c < NC; ++c) {
      s  += tot[c]*a2s_g[c];
      dd += tot[c]*a2d_g[c];
      g2[(size_t)n*NC + c] = tot[c];
    }
    as2[n] = s; ad2[n] = dd;
  }
}

// ---------------- attn2: wave-per-dst softmax + 18-ch gather ----------------
__global__ __launch_bounds__(256) void attn2_k(const float* __restrict__ g2,
    const float* __restrict__ as2, const float* __restrict__ ad2,
    const int* __restrict__ off, const int* __restrict__ csr,
    const float* __restrict__ b2, float* __restrict__ out, int N){
  int t = threadIdx.x, lane = t & 63, wid = t >> 6;
  int d = blockIdx.x*4 + wid;
  if (d >= N) return;
  int beg = off[d], end = off[d+1];
  float adv = ad2[d];
  float lm = -1e30f;
  for (int j = beg + lane; j < end; j += 64)
    lm = fmaxf(lm, lrelu(as2[csr[j]] + adv));
  #pragma unroll
  for (int o = 32; o > 0; o >>= 1) lm = fmaxf(lm, __shfl_xor(lm, o, 64));
  float lz = 0.f;
  for (int j = beg + lane; j < end; j += 64)
    lz += __expf(lrelu(as2[csr[j]] + adv) - lm);
  #pragma unroll
  for (int o = 32; o > 0; o >>= 1) lz += __shfl_xor(lz, o, 64);
  float zinv = 1.f / (lz + 1e-16f);
  if (lane < NC) {
    float acc = 0.f;
    for (int j = beg; j < end; ++j) {
      int s = csr[j];
      float w = __expf(lrelu(as2[s] + adv) - lm) * zinv;
      acc += w * g2[(size_t)s*NC + lane];
    }
    out[(size_t)d*NC + lane] = acc + b2[lane];
  }
}

extern "C" void kernel_launch(void* const* d_in, const int* in_sizes, int n_in,
                              void* d_out, int out_size, void* d_ws, size_t ws_size,
                              hipStream_t stream){
  const float* x   = (const float*)d_in[0];
  const int*   ei  = (const int*)d_in[1];
  const float* W1  = (const float*)d_in[2];
  const float* a1s = (const float*)d_in[3];
  const float* a1d = (const float*)d_in[4];
  const float* b1  = (const float*)d_in[5];
  const float* W2  = (const float*)d_in[6];
  const float* a2s = (const float*)d_in[7];
  const float* a2d = (const float*)d_in[8];
  const float* b2  = (const float*)d_in[9];
  float* out = (float*)d_out;
  int N  = in_sizes[0] / FIN;
  int E0 = in_sizes[1] / 2;
  int Etot = E0 + N;

  // fp32 region
  float* as1 = (float*)d_ws;                 // N*8
  float* ad1 = as1 + (size_t)N*NH;           // N*8
  float* g2  = ad1 + (size_t)N*NH;           // N*18
  float* as2 = g2 + (size_t)N*NC;            // N
  float* ad2 = as2 + N;                      // N
  // bf16 region (16B aligned: all prior sizes are multiples of 4 floats for N=20000)
  unsigned short* g1b = (unsigned short*)(ad2 + N);       // N*1024
  unsigned short* hb  = g1b + (size_t)N*HD;               // N*1024
  // int region
  int* deg    = (int*)(hb + (size_t)N*HD);
  int* off    = deg + N;
  int* cursor = off + N + 1;
  int* csr    = cursor + N;

  hipMemsetAsync(deg, 0, sizeof(int)*(size_t)N, stream);
  hist_k<<<(Etot+255)/256, 256, 0, stream>>>(ei, E0, N, deg);
  scan_k<<<1, 1024, 0, stream>>>(deg, N, off, cursor);
  scatter_k<<<(Etot+255)/256, 256, 0, stream>>>(ei, E0, N, cursor, csr);

  dim3 g1grid((N+63)/64, HD/64);
  gemm1_k<<<g1grid, 256, 0, stream>>>(x, W1, g1b, N);
  alpha1_k<<<N, 256, 0, stream>>>(g1b, a1s, a1d, as1, ad1, N);
  attn1_k<<<(N+3)/4, 256, 0, stream>>>(g1b, as1, ad1, off, csr, b1, hb, N);
  gemm2_k<<<(N+63)/64, 256, 0, stream>>>(hb, W2, a2s, a2d, g2, as2, ad2, N);
  attn2_k<<<(N+3)/4, 256, 0, stream>>>(g2, as2, ad2, off, csr, b2, out, N);
}

// Round 4
// 289.635 us; speedup vs baseline: 2.1878x; 1.4281x over previous
//
#include <hip/hip_runtime.h>
#include <math.h>

#define FIN 128
#define NH 8
#define HC 128
#define HD (NH*HC)   // 1024
#define NC 18
#define NEG 0.2f

typedef __attribute__((ext_vector_type(8))) short bf16x8;
typedef __attribute__((ext_vector_type(4))) float f32x4;

__device__ __forceinline__ float lrelu(float v){ return v > 0.f ? v : NEG*v; }

// round-to-nearest-even fp32 -> bf16
__device__ __forceinline__ unsigned short f2b(float f){
  unsigned u = __float_as_uint(f);
  unsigned r = (u + 0x7fffu + ((u >> 16) & 1u)) >> 16;
  return (unsigned short)r;
}
__device__ __forceinline__ float b2f_lo(unsigned u){ return __uint_as_float(u << 16); }
__device__ __forceinline__ float b2f_hi(unsigned u){ return __uint_as_float(u & 0xffff0000u); }

// ---------------- CSR build (by destination) ----------------
__global__ void hist_k(const int* __restrict__ ei, int E0, int N, int* __restrict__ deg){
  int e = blockIdx.x*256 + threadIdx.x;
  int tot = E0 + N;
  if (e >= tot) return;
  int dst = (e < E0) ? ei[E0 + e] : (e - E0);
  atomicAdd(&deg[dst], 1);
}

__global__ __launch_bounds__(1024) void scan_k(const int* __restrict__ deg, int N,
                                               int* __restrict__ off, int* __restrict__ cursor){
  __shared__ int wsum[16];
  __shared__ int s_carry;
  int t = threadIdx.x, lane = t & 63, wid = t >> 6;
  if (t == 0) s_carry = 0;
  __syncthreads();
  for (int base = 0; base < N; base += 1024) {
    int i = base + t;
    int v = (i < N) ? deg[i] : 0;
    int x = v;
    #pragma unroll
    for (int o = 1; o < 64; o <<= 1) {
      int y = __shfl_up(x, o, 64);
      if (lane >= o) x += y;
    }
    if (lane == 63) wsum[wid] = x;
    __syncthreads();
    if (wid == 0) {
      int wv = (lane < 16) ? wsum[lane] : 0;
      #pragma unroll
      for (int o = 1; o < 16; o <<= 1) {
        int y = __shfl_up(wv, o, 64);
        if (lane >= o) wv += y;
      }
      if (lane < 16) wsum[lane] = wv;
    }
    __syncthreads();
    int woff = (wid > 0) ? wsum[wid-1] : 0;
    int carry = s_carry;
    int exc = x - v + woff + carry;
    if (i < N) { off[i] = exc; cursor[i] = exc; }
    __syncthreads();
    if (t == 1023) s_carry = carry + wsum[15];
    __syncthreads();
  }
  if (t == 0) off[N] = s_carry;
}

__global__ void scatter_k(const int* __restrict__ ei, int E0, int N,
                          int* __restrict__ cursor, int* __restrict__ csr){
  int e = blockIdx.x*256 + threadIdx.x;
  int tot = E0 + N;
  if (e >= tot) return;
  int src, dst;
  if (e < E0) { src = ei[e]; dst = ei[E0 + e]; }
  else        { src = e - E0; dst = src; }
  int p = atomicAdd(&cursor[dst], 1);
  csr[p] = src;
}

// ---------------- converts: x -> bf16, W1 -> bf16 transposed [n][k] ----------------
__global__ __launch_bounds__(256) void xcvt_k(const float* __restrict__ x,
                                              unsigned short* __restrict__ xb, int total8){
  int i = blockIdx.x*256 + threadIdx.x;
  if (i >= total8) return;
  const float4* p = (const float4*)x + (size_t)i*2;
  float4 a = p[0], b = p[1];
  uint4 o;
  o.x = (unsigned)f2b(a.x) | ((unsigned)f2b(a.y) << 16);
  o.y = (unsigned)f2b(a.z) | ((unsigned)f2b(a.w) << 16);
  o.z = (unsigned)f2b(b.x) | ((unsigned)f2b(b.y) << 16);
  o.w = (unsigned)f2b(b.z) | ((unsigned)f2b(b.w) << 16);
  ((uint4*)xb)[i] = o;
}

__global__ __launch_bounds__(256) void w1t_k(const float* __restrict__ W1,
                                             unsigned short* __restrict__ w1t){
  __shared__ unsigned short sT[FIN][64+2];
  int t = threadIdx.x;
  int n0 = blockIdx.x * 64;
  #pragma unroll
  for (int i = 0; i < 32; ++i) {
    int idx = i*256 + t;
    int k = idx >> 6, nl = idx & 63;
    sT[k][nl] = f2b(W1[(size_t)k*HD + n0 + nl]);
  }
  __syncthreads();
  #pragma unroll
  for (int i = 0; i < 16; ++i) {
    int nl = i*4 + (t >> 6);
    int kp = t & 63;
    unsigned u = (unsigned)sT[2*kp][nl] | ((unsigned)sT[2*kp+1][nl] << 16);
    *(unsigned*)&w1t[(size_t)(n0+nl)*FIN + 2*kp] = u;
  }
}

// ---------------- GEMM1 (MFMA bf16): g1b = bf16(xb @ w1t^T), K=128 ----------------
__global__ __launch_bounds__(256) void gemm1_mfma_k(const unsigned short* __restrict__ xb,
                                                    const unsigned short* __restrict__ w1t,
                                                    unsigned short* __restrict__ g1b, int N){
  __shared__ unsigned short sA[128][136];  // [m][k], pad 8 bf16 -> row stride 272B (2-way bank, free)
  __shared__ unsigned short sB[128][136];  // [n][k]
  int t = threadIdx.x, lane = t & 63, wid = t >> 6;
  int bm = blockIdx.x * 128;
  int bn = blockIdx.y * 128;
  // stage A (rows of xb)
  #pragma unroll
  for (int i = 0; i < 2; ++i) {
    int idx = i*256 + t;
    int row = idx >> 2, seg = idx & 3;     // seg = 32 bf16 = 64B
    int gm = bm + row;
    uint4 a0,a1,a2,a3;
    if (gm < N) {
      const uint4* gp = (const uint4*)(xb + (size_t)gm*FIN + seg*32);
      a0 = gp[0]; a1 = gp[1]; a2 = gp[2]; a3 = gp[3];
    } else {
      a0 = a1 = a2 = a3 = make_uint4(0,0,0,0);
    }
    uint4* lp = (uint4*)&sA[row][seg*32];
    lp[0]=a0; lp[1]=a1; lp[2]=a2; lp[3]=a3;
  }
  // stage B (rows of w1t = columns of W1)
  #pragma unroll
  for (int i = 0; i < 2; ++i) {
    int idx = i*256 + t;
    int row = idx >> 2, seg = idx & 3;
    const uint4* gp = (const uint4*)(w1t + (size_t)(bn + row)*FIN + seg*32);
    uint4* lp = (uint4*)&sB[row][seg*32];
    lp[0]=gp[0]; lp[1]=gp[1]; lp[2]=gp[2]; lp[3]=gp[3];
  }
  __syncthreads();
  int wr = wid >> 1, wc = wid & 1;
  int lr = lane & 15, kb = lane >> 4;
  f32x4 acc[4][4];
  #pragma unroll
  for (int mi = 0; mi < 4; ++mi)
    #pragma unroll
    for (int ni = 0; ni < 4; ++ni) {
      f32x4 z = {0.f, 0.f, 0.f, 0.f};
      acc[mi][ni] = z;
    }
  #pragma unroll
  for (int ks = 0; ks < 4; ++ks) {
    int ko = ks*32 + kb*8;
    bf16x8 a[4], b[4];
    #pragma unroll
    for (int mi = 0; mi < 4; ++mi)
      a[mi] = *(const bf16x8*)&sA[wr*64 + mi*16 + lr][ko];
    #pragma unroll
    for (int ni = 0; ni < 4; ++ni)
      b[ni] = *(const bf16x8*)&sB[wc*64 + ni*16 + lr][ko];
    #pragma unroll
    for (int mi = 0; mi < 4; ++mi)
      #pragma unroll
      for (int ni = 0; ni < 4; ++ni)
        acc[mi][ni] = __builtin_amdgcn_mfma_f32_16x16x32_bf16(a[mi], b[ni], acc[mi][ni], 0, 0, 0);
  }
  // epilogue: D col=lane&15, row=(lane>>4)*4+reg  (m89-verified)
  #pragma unroll
  for (int mi = 0; mi < 4; ++mi)
    #pragma unroll
    for (int ni = 0; ni < 4; ++ni) {
      int col = bn + wc*64 + ni*16 + lr;
      #pragma unroll
      for (int r = 0; r < 4; ++r) {
        int row = bm + wr*64 + mi*16 + kb*4 + r;
        if (row < N) g1b[(size_t)row*HD + col] = f2b(acc[mi][ni][r]);
      }
    }
}

// ---------------- alpha1: per-node attention logits from bf16 h ----------------
__global__ __launch_bounds__(256) void alpha1_k(const unsigned short* __restrict__ g1b,
    const float* __restrict__ a1s, const float* __restrict__ a1d,
    float* __restrict__ as1, float* __restrict__ ad1, int N){
  int n = blockIdx.x, t = threadIdx.x;
  int h = t >> 5;
  int cc = (t & 31) << 2;
  uint2 raw = *(const uint2*)(g1b + (size_t)n*HD + (t << 2));
  float h0 = b2f_lo(raw.x), h1 = b2f_hi(raw.x), h2 = b2f_lo(raw.y), h3 = b2f_hi(raw.y);
  float4 av = *(const float4*)&a1s[h*HC + cc];
  float4 bv = *(const float4*)&a1d[h*HC + cc];
  float s = h0*av.x + h1*av.y + h2*av.z + h3*av.w;
  float d = h0*bv.x + h1*bv.y + h2*bv.z + h3*bv.w;
  #pragma unroll
  for (int o = 16; o > 0; o >>= 1) {
    s += __shfl_xor(s, o, 32);
    d += __shfl_xor(d, o, 32);
  }
  if ((t & 31) == 0) { as1[n*NH + h] = s; ad1[n*NH + h] = d; }
}

// ---------------- attn1: wave-per-dst online softmax + bf16 weighted gather ----------------
__global__ __launch_bounds__(256) void attn1_k(const unsigned short* __restrict__ g1b,
    const float* __restrict__ as1, const float* __restrict__ ad1,
    const int* __restrict__ off, const int* __restrict__ csr,
    const float* __restrict__ b1, unsigned short* __restrict__ hb, int N){
  int t = threadIdx.x, lane = t & 63, wid = t >> 6;
  int d = blockIdx.x*4 + wid;
  if (d >= N) return;
  int beg = off[d], end = off[d+1], deg = end - beg;

  int hr = lane & 7;
  float adr = ad1[d*NH + hr];
  float m = -1e30f, z = 0.f;
  for (int j = lane >> 3; j < deg; j += 8) {
    int s = csr[beg + j];
    float e = lrelu(as1[s*NH + hr] + adr);
    if (e > m) { z = z*__expf(m - e) + 1.f; m = e; }
    else       { z += __expf(e - m); }
  }
  #pragma unroll
  for (int o = 8; o < 64; o <<= 1) {
    float mo = __shfl_xor(m, o, 64), zo = __shfl_xor(z, o, 64);
    float mn = fmaxf(m, mo);
    z = z*__expf(m - mn) + zo*__expf(mo - mn);
    m = mn;
  }
  int hg = lane >> 3;
  float mg   = __shfl(m,   hg, 64);
  float zg   = __shfl(z,   hg, 64);
  float adg  = __shfl(adr, hg, 64);
  float zinv = 1.f / (zg + 1e-16f);

  float acc[16];
  #pragma unroll
  for (int i = 0; i < 16; ++i) acc[i] = 0.f;
  for (int j = 0; j < deg; ++j) {
    int s = csr[beg + j];
    float e = lrelu(as1[s*NH + hg] + adg);
    float w = __expf(e - mg) * zinv;
    const uint4* p = (const uint4*)(g1b + (size_t)s*HD) + lane*2;
    uint4 r0 = p[0], r1 = p[1];
    acc[ 0] += w*b2f_lo(r0.x); acc[ 1] += w*b2f_hi(r0.x);
    acc[ 2] += w*b2f_lo(r0.y); acc[ 3] += w*b2f_hi(r0.y);
    acc[ 4] += w*b2f_lo(r0.z); acc[ 5] += w*b2f_hi(r0.z);
    acc[ 6] += w*b2f_lo(r0.w); acc[ 7] += w*b2f_hi(r0.w);
    acc[ 8] += w*b2f_lo(r1.x); acc[ 9] += w*b2f_hi(r1.x);
    acc[10] += w*b2f_lo(r1.y); acc[11] += w*b2f_hi(r1.y);
    acc[12] += w*b2f_lo(r1.z); acc[13] += w*b2f_hi(r1.z);
    acc[14] += w*b2f_lo(r1.w); acc[15] += w*b2f_hi(r1.w);
  }
  int cb = lane*16;
  uint o[8];
  #pragma unroll
  for (int q = 0; q < 4; ++q) {
    float4 bv = *(const float4*)&b1[cb + q*4];
    float v0 = fmaxf(acc[q*4+0] + bv.x, 0.f);
    float v1 = fmaxf(acc[q*4+1] + bv.y, 0.f);
    float v2 = fmaxf(acc[q*4+2] + bv.z, 0.f);
    float v3 = fmaxf(acc[q*4+3] + bv.w, 0.f);
    o[q*2+0] = (unsigned)f2b(v0) | ((unsigned)f2b(v1) << 16);
    o[q*2+1] = (unsigned)f2b(v2) | ((unsigned)f2b(v3) << 16);
  }
  uint4* dst = (uint4*)(hb + (size_t)d*HD) + lane*2;
  dst[0] = make_uint4(o[0], o[1], o[2], o[3]);
  dst[1] = make_uint4(o[4], o[5], o[6], o[7]);
}

// ---------------- GEMM2 (+alpha2 fused): g2 = hrelu @ W2, W2 staged bf16 in LDS ----------------
__global__ __launch_bounds__(256) void gemm2_k(const unsigned short* __restrict__ hb,
    const float* __restrict__ W2, const float* __restrict__ a2s_g, const float* __restrict__ a2d_g,
    float* __restrict__ g2, float* __restrict__ as2, float* __restrict__ ad2, int N){
  __shared__ unsigned short sW[HD*NC];       // 36.9 KB
  __shared__ float red[4][64][NC+1];         // 19.5 KB
  int t = threadIdx.x, lane = t & 63, wid = t >> 6;
  int n0 = blockIdx.x * 64;
  #pragma unroll
  for (int i = 0; i < (HD*NC)/256; ++i) {
    int idx = i*256 + t;
    sW[idx] = f2b(W2[idx]);
  }
  __syncthreads();
  int n = n0 + lane;
  bool valid = (n < N);
  float acc[NC];
  #pragma unroll
  for (int c = 0; c < NC; ++c) acc[c] = 0.f;
  int k0beg = wid * 256;
  for (int k0 = k0beg; k0 < k0beg + 256; k0 += 8) {
    uint4 raw = valid ? *(const uint4*)(hb + (size_t)n*HD + k0) : make_uint4(0,0,0,0);
    float a[8];
    a[0]=b2f_lo(raw.x); a[1]=b2f_hi(raw.x); a[2]=b2f_lo(raw.y); a[3]=b2f_hi(raw.y);
    a[4]=b2f_lo(raw.z); a[5]=b2f_hi(raw.z); a[6]=b2f_lo(raw.w); a[7]=b2f_hi(raw.w);
    #pragma unroll
    for (int kk = 0; kk < 8; ++kk) {
      const unsigned* wr = (const unsigned*)(sW + (size_t)(k0 + kk)*NC);
      float av = a[kk];
      #pragma unroll
      for (int c2 = 0; c2 < NC/2; ++c2) {
        unsigned u = wr[c2];
        acc[2*c2+0] += av * b2f_lo(u);
        acc[2*c2+1] += av * b2f_hi(u);
      }
    }
  }
  #pragma unroll
  for (int c = 0; c < NC; ++c) red[wid][lane][c] = acc[c];
  __syncthreads();
  if (wid == 0 && valid) {
    float tot[NC];
    #pragma unroll
    for (int c = 0; c < NC; ++c)
      tot[c] = red[0][lane][c] + red[1][lane][c] + red[2][lane][c] + red[3][lane][c];
    float s = 0.f, dd = 0.f;
    #pragma unroll
    for (int c = 0; c < NC; ++c) {
      s  += tot[c]*a2s_g[c];
      dd += tot[c]*a2d_g[c];
      g2[(size_t)n*NC + c] = tot[c];
    }
    as2[n] = s; ad2[n] = dd;
  }
}

// ---------------- attn2: wave-per-dst softmax + 18-ch gather ----------------
__global__ __launch_bounds__(256) void attn2_k(const float* __restrict__ g2,
    const float* __restrict__ as2, const float* __restrict__ ad2,
    const int* __restrict__ off, const int* __restrict__ csr,
    const float* __restrict__ b2, float* __restrict__ out, int N){
  int t = threadIdx.x, lane = t & 63, wid = t >> 6;
  int d = blockIdx.x*4 + wid;
  if (d >= N) return;
  int beg = off[d], end = off[d+1];
  float adv = ad2[d];
  float lm = -1e30f;
  for (int j = beg + lane; j < end; j += 64)
    lm = fmaxf(lm, lrelu(as2[csr[j]] + adv));
  #pragma unroll
  for (int o = 32; o > 0; o >>= 1) lm = fmaxf(lm, __shfl_xor(lm, o, 64));
  float lz = 0.f;
  for (int j = beg + lane; j < end; j += 64)
    lz += __expf(lrelu(as2[csr[j]] + adv) - lm);
  #pragma unroll
  for (int o = 32; o > 0; o >>= 1) lz += __shfl_xor(lz, o, 64);
  float zinv = 1.f / (lz + 1e-16f);
  if (lane < NC) {
    float acc = 0.f;
    for (int j = beg; j < end; ++j) {
      int s = csr[j];
      float w = __expf(lrelu(as2[s] + adv) - lm) * zinv;
      acc += w * g2[(size_t)s*NC + lane];
    }
    out[(size_t)d*NC + lane] = acc + b2[lane];
  }
}

extern "C" void kernel_launch(void* const* d_in, const int* in_sizes, int n_in,
                              void* d_out, int out_size, void* d_ws, size_t ws_size,
                              hipStream_t stream){
  const float* x   = (const float*)d_in[0];
  const int*   ei  = (const int*)d_in[1];
  const float* W1  = (const float*)d_in[2];
  const float* a1s = (const float*)d_in[3];
  const float* a1d = (const float*)d_in[4];
  const float* b1  = (const float*)d_in[5];
  const float* W2  = (const float*)d_in[6];
  const float* a2s = (const float*)d_in[7];
  const float* a2d = (const float*)d_in[8];
  const float* b2  = (const float*)d_in[9];
  float* out = (float*)d_out;
  int N  = in_sizes[0] / FIN;
  int E0 = in_sizes[1] / 2;
  int Etot = E0 + N;

  // fp32 region
  float* as1 = (float*)d_ws;                 // N*8
  float* ad1 = as1 + (size_t)N*NH;           // N*8
  float* g2  = ad1 + (size_t)N*NH;           // N*18
  float* as2 = g2 + (size_t)N*NC;            // N
  float* ad2 = as2 + N;                      // N
  // bf16 region
  unsigned short* g1b = (unsigned short*)(ad2 + N);       // N*1024
  unsigned short* hb  = g1b + (size_t)N*HD;               // N*1024
  // int region
  int* deg    = (int*)(hb + (size_t)N*HD);
  int* off    = deg + N;
  int* cursor = off + N + 4;   // +4 pad keeps downstream 16B alignment
  int* csr    = cursor + N;
  // converted inputs live inside hb's region (hb is only written by attn1,
  // which runs after gemm1 has consumed xb/w1t)
  unsigned short* xb  = hb;                   // N*FIN bf16 = 5.12 MB
  unsigned short* w1t = hb + (size_t)N*FIN;   // HD*FIN bf16 = 0.26 MB

  hipMemsetAsync(deg, 0, sizeof(int)*(size_t)N, stream);
  hist_k<<<(Etot+255)/256, 256, 0, stream>>>(ei, E0, N, deg);
  scan_k<<<1, 1024, 0, stream>>>(deg, N, off, cursor);
  scatter_k<<<(Etot+255)/256, 256, 0, stream>>>(ei, E0, N, cursor, csr);

  int total8 = N*FIN/8;
  xcvt_k<<<(total8+255)/256, 256, 0, stream>>>(x, xb, total8);
  w1t_k<<<HD/64, 256, 0, stream>>>(W1, w1t);

  dim3 g1grid((N+127)/128, HD/128);
  gemm1_mfma_k<<<g1grid, 256, 0, stream>>>(xb, w1t, g1b, N);
  alpha1_k<<<N, 256, 0, stream>>>(g1b, a1s, a1d, as1, ad1, N);
  attn1_k<<<(N+3)/4, 256, 0, stream>>>(g1b, as1, ad1, off, csr, b1, hb, N);
  gemm2_k<<<(N+63)/64, 256, 0, stream>>>(hb, W2, a2s, a2d, g2, as2, ad2, N);
  attn2_k<<<(N+3)/4, 256, 0, stream>>>(g2, as2, ad2, off, csr, b2, out, N);
}